// Round 2
// baseline (1459.534 us; speedup 1.0000x reference)
//
#include <hip/hip_runtime.h>
#include <hip/hip_bf16.h>

#define MUL 32
#define F4 128            // 4*MUL
#define FEAT 256          // edge feature width
#define NB 10
#define NH 100

#define INV_SQRT32 0.17677669529663687f
#define INV_SQRT10 0.31622776601683794f
#define INV_SQRT100 0.1f
#define INV_SQRT3 0.5773502691896258f
#define AGG_SCALE 0.25f   // 1/sqrt(16)
#define INV8 0.125f       // 1/sqrt(64)
#define C_S 0.3826834323650898f
#define C_X 0.9238795325112867f

__device__ __forceinline__ float bf2f(__hip_bfloat16 v) { return __bfloat162float(v); }

// flag: 1 = inputs are fp32, 0 = inputs are bf16
__device__ __forceinline__ float ldin(const void* p, size_t i, int f) {
    return f ? ((const float*)p)[i]
             : __bfloat162float(((const __hip_bfloat16*)p)[i]);
}

// ---------------------------------------------------------------------------
// Kernel 0: detect input dtype from node_attr (all ones).
// fp32 word = 0x3F800000 ; bf16 pair = 0x3F803F80
// ---------------------------------------------------------------------------
__global__ void detect_dtype_kernel(const void* __restrict__ node_attr, int* __restrict__ flag) {
    unsigned w = *(const unsigned*)node_attr;
    *flag = (w == 0x3F800000u) ? 1 : 0;
}

// ---------------------------------------------------------------------------
// Kernel 1: y = fctp(x0,x1, attr, W_l10, W_l11)   -> fp32 [N,128]
// layout: y[n][c] : c<32 -> y0[c]; c>=32 -> y1[u][d] at c = 32 + u*3 + d
// ---------------------------------------------------------------------------
__global__ __launch_bounds__(256) void node_y_kernel(
    const void* __restrict__ node_input,  // N x 128
    const void* __restrict__ node_attr,   // N
    const void* __restrict__ Wl10,        // 32x32
    const void* __restrict__ Wl11,        // 32x32
    const int* __restrict__ flagp,
    float* __restrict__ y, int N)
{
    __shared__ float sW0[32 * 32];
    __shared__ float sW1[32 * 32];
    __shared__ float sX[2][128];
    int f = *flagp;
    int t = threadIdx.x;
    for (int i = t; i < 1024; i += 256) {
        sW0[i] = ldin(Wl10, i, f);
        sW1[i] = ldin(Wl11, i, f);
    }
    int n0 = blockIdx.x * 2;
    {
        int ln = t >> 7, c = t & 127;
        int n = n0 + ln;
        sX[ln][c] = (n < N) ? ldin(node_input, (size_t)n * F4 + c, f) : 0.f;
    }
    __syncthreads();
    int ln = t >> 7, c = t & 127;
    int n = n0 + ln;
    if (n >= N) return;
    float attr = ldin(node_attr, n, f);
    float acc = 0.f;
    if (c < 32) {
#pragma unroll
        for (int u = 0; u < 32; u++) acc += sX[ln][u] * sW0[u * 32 + c];
    } else {
        int i = c - 32;
        int u0 = i / 3, d = i - u0 * 3;
#pragma unroll
        for (int u = 0; u < 32; u++) acc += sX[ln][32 + u * 3 + d] * sW1[u * 32 + u0];
    }
    y[(size_t)n * F4 + c] = acc * attr * INV_SQRT32;
}

// ---------------------------------------------------------------------------
// Kernel 2: per-edge MLP  w = (silu(ele @ Wfc1 /sqrt(10)) @ Wfc2) / 10
// one thread per edge; h[100] in registers; Wfc2 fp32 in LDS (broadcast b128).
// writes bf16 w (chunk-local) [len x 128]  (internal buffer, always bf16)
// ---------------------------------------------------------------------------
__global__ __launch_bounds__(256) void edge_mlp_kernel(
    const void* __restrict__ ele,   // E x 10
    const void* __restrict__ Wfc1,  // 10 x 100
    const void* __restrict__ Wfc2,  // 100 x 128
    const int* __restrict__ flagp,
    __hip_bfloat16* __restrict__ w_out,  // chunk_len x 128
    int e_start, int e_end)
{
    __shared__ float sW1[NB * NH];
    __shared__ __align__(16) float sW2[NH * F4];
    int f = *flagp;
    int t = threadIdx.x;
    for (int i = t; i < NB * NH; i += 256) sW1[i] = ldin(Wfc1, i, f);
    for (int i = t; i < NH * F4; i += 256) sW2[i] = ldin(Wfc2, i, f);
    __syncthreads();
    int e = e_start + blockIdx.x * 256 + t;
    if (e >= e_end) return;

    float el[NB];
#pragma unroll
    for (int i = 0; i < NB; i++) el[i] = ldin(ele, (size_t)e * NB + i, f);

    float h[NH];
#pragma unroll
    for (int j = 0; j < NH; j++) {
        float a = 0.f;
#pragma unroll
        for (int i = 0; i < NB; i++) a += el[i] * sW1[i * NH + j];
        a *= INV_SQRT10;
        h[j] = a / (1.f + __expf(-a));   // silu
    }

    size_t wbase = (size_t)(e - e_start) * F4;
    for (int k4 = 0; k4 < F4 / 4; k4++) {
        float a0 = 0.f, a1 = 0.f, a2 = 0.f, a3 = 0.f;
        const float* w2p = &sW2[k4 * 4];
#pragma unroll
        for (int j = 0; j < NH; j++) {
            float4 wv = *(const float4*)(w2p + j * F4);  // broadcast b128
            a0 += h[j] * wv.x;
            a1 += h[j] * wv.y;
            a2 += h[j] * wv.z;
            a3 += h[j] * wv.w;
        }
        __hip_bfloat16 b0 = __float2bfloat16(a0 * INV_SQRT100);
        __hip_bfloat16 b1 = __float2bfloat16(a1 * INV_SQRT100);
        __hip_bfloat16 b2 = __float2bfloat16(a2 * INV_SQRT100);
        __hip_bfloat16 b3 = __float2bfloat16(a3 * INV_SQRT100);
        ushort4 pk;
        pk.x = *(unsigned short*)&b0;
        pk.y = *(unsigned short*)&b1;
        pk.z = *(unsigned short*)&b2;
        pk.w = *(unsigned short*)&b3;
        *(ushort4*)(&w_out[wbase + k4 * 4]) = pk;
    }
}

// ---------------------------------------------------------------------------
// Kernel 3: edge features + scatter-add into agg [N x 256] fp32
// 16 edges per block; thread = feature channel (0..255)
// feature layout: [mid0a(32) | mid0b(32) | mid1a(96: u*3+d) | mid1b(96)]
// ---------------------------------------------------------------------------
#define TE 16
__global__ __launch_bounds__(256) void scatter_kernel(
    const __hip_bfloat16* __restrict__ w_ws,  // chunk_len x 128 (internal, bf16)
    const float* __restrict__ y,              // N x 128 (internal, fp32)
    const void* __restrict__ eattr,           // E x 4
    const int* __restrict__ esrc,
    const int* __restrict__ edst,
    const int* __restrict__ flagp,
    float* __restrict__ agg,                  // N x 256
    int e_start, int e_end)
{
    __shared__ float sW[TE][F4];
    __shared__ float sY[TE][F4];
    __shared__ float sEa[TE][4];
    __shared__ int sSrc[TE];
    __shared__ int sDst[TE];
    int f = *flagp;
    int t = threadIdx.x;
    int e0 = e_start + blockIdx.x * TE;
    int ne = e_end - e0;
    if (ne > TE) ne = TE;
    if (ne <= 0) return;
    if (t < ne) {
        sSrc[t] = esrc[e0 + t];
        sDst[t] = edst[e0 + t];
    }
    for (int i = t; i < ne * 4; i += 256) {
        int e = i >> 2, j = i & 3;
        sEa[e][j] = ldin(eattr, (size_t)(e0 + e) * 4 + j, f);
    }
    for (int i = t; i < ne * F4; i += 256) {
        int e = i >> 7, c = i & 127;
        sW[e][c] = bf2f(w_ws[(size_t)(e0 - e_start + e) * F4 + c]);
    }
    __syncthreads();
    for (int i = t; i < ne * F4; i += 256) {
        int e = i >> 7, c = i & 127;
        sY[e][c] = y[(size_t)sSrc[e] * F4 + c];
    }
    __syncthreads();

    int c = t;  // 0..255 feature channel
    int wi, yi, ai, mode;
    if (c < 32) { wi = c; yi = c; ai = 0; mode = 0; }
    else if (c < 64) { int u = c - 32; wi = 96 + u; yi = 32 + u * 3; ai = 0; mode = 1; }
    else if (c < 160) { int i = c - 64; int u = i / 3, d = i - u * 3; wi = 32 + u; yi = u; ai = 1 + d; mode = 0; }
    else { int i = c - 160; int u = i / 3, d = i - u * 3; wi = 64 + u; yi = 32 + u * 3 + d; ai = 0; mode = 0; }
    float scale = AGG_SCALE * (mode ? INV_SQRT3 : 1.f);

    for (int e = 0; e < ne; e++) {
        float fv;
        if (mode == 0) {
            fv = sW[e][wi] * sY[e][yi] * sEa[e][ai];
        } else {
            fv = sW[e][wi] * (sY[e][yi] * sEa[e][1] + sY[e][yi + 1] * sEa[e][2] + sY[e][yi + 2] * sEa[e][3]);
        }
        atomicAdd(&agg[(size_t)sDst[e] * FEAT + c], fv * scale);
    }
}

// ---------------------------------------------------------------------------
// Kernel 4: out = attr*(c_s * sc + c_x * l2(agg)); dtype per flag
// ---------------------------------------------------------------------------
__global__ __launch_bounds__(256) void out_kernel(
    const void* __restrict__ node_input,  // N x 128
    const void* __restrict__ node_attr,   // N
    const void* __restrict__ Wsc0,        // 32x32
    const void* __restrict__ Wsc1,        // 32x32
    const void* __restrict__ Wl20,        // 64x32
    const void* __restrict__ Wl21,        // 64x32
    const float* __restrict__ agg,        // N x 256
    const int* __restrict__ flagp,
    void* __restrict__ out, int N)
{
    __shared__ float sWs0[1024], sWs1[1024];
    __shared__ float sW20[2048], sW21[2048];
    __shared__ float sX[2][128];
    __shared__ float sA[2][256];
    int f = *flagp;
    int t = threadIdx.x;
    for (int i = t; i < 1024; i += 256) {
        sWs0[i] = ldin(Wsc0, i, f);
        sWs1[i] = ldin(Wsc1, i, f);
    }
    for (int i = t; i < 2048; i += 256) {
        sW20[i] = ldin(Wl20, i, f);
        sW21[i] = ldin(Wl21, i, f);
    }
    int n0 = blockIdx.x * 2;
    {
        int ln = t >> 7, c = t & 127;
        int n = n0 + ln;
        sX[ln][c] = (n < N) ? ldin(node_input, (size_t)n * F4 + c, f) : 0.f;
    }
    for (int i = t; i < 512; i += 256) {
        int ln = i >> 8, c = i & 255;
        int n = n0 + ln;
        sA[ln][c] = (n < N) ? agg[(size_t)n * FEAT + c] : 0.f;
    }
    __syncthreads();
    int ln = t >> 7, c = t & 127;
    int n = n0 + ln;
    if (n >= N) return;
    float attr = ldin(node_attr, n, f);
    float s, z;
    if (c < 32) {
        float as = 0.f, az = 0.f;
#pragma unroll
        for (int u = 0; u < 32; u++) as += sX[ln][u] * sWs0[u * 32 + c];
#pragma unroll
        for (int u = 0; u < 64; u++) az += sA[ln][u] * sW20[u * 32 + c];
        s = as * INV_SQRT32;
        z = az * INV8;
    } else {
        int i = c - 32;
        int u0 = i / 3, d = i - u0 * 3;
        float as = 0.f, az = 0.f;
#pragma unroll
        for (int u = 0; u < 32; u++) as += sX[ln][32 + u * 3 + d] * sWs1[u * 32 + u0];
#pragma unroll
        for (int u = 0; u < 64; u++) az += sA[ln][64 + u * 3 + d] * sW21[u * 32 + u0];
        s = as * INV_SQRT32;
        z = az * INV8;
    }
    float val = attr * (C_S * s + C_X * z);
    size_t oi = (size_t)n * F4 + c;
    if (f) ((float*)out)[oi] = val;
    else   ((__hip_bfloat16*)out)[oi] = __float2bfloat16(val);
}

// ---------------------------------------------------------------------------
extern "C" void kernel_launch(void* const* d_in, const int* in_sizes, int n_in,
                              void* d_out, int out_size, void* d_ws, size_t ws_size,
                              hipStream_t stream) {
    const void* node_input = d_in[0];
    const void* node_attr  = d_in[1];
    const int* edge_src    = (const int*)d_in[2];
    const int* edge_dst    = (const int*)d_in[3];
    const void* edge_attr  = d_in[4];
    const void* ele        = d_in[5];
    const void* Wsc0       = d_in[6];
    const void* Wsc1       = d_in[7];
    const void* Wl10       = d_in[8];
    const void* Wl11       = d_in[9];
    const void* Wl20       = d_in[10];
    const void* Wl21       = d_in[11];
    const void* Wfc1       = d_in[12];
    const void* Wfc2       = d_in[13];

    int N = in_sizes[0] / F4;   // 50000
    int E = in_sizes[2];        // 800000

    char* ws = (char*)d_ws;
    int*   flag = (int*)ws;                                    // 64 B slot
    float* y    = (float*)(ws + 64);                           // N*128 fp32 = 25.6 MB
    size_t y_bytes = (size_t)N * F4 * 4;
    float* agg  = (float*)(ws + 64 + y_bytes);                 // N*256 fp32 = 51.2 MB
    size_t agg_bytes = (size_t)N * FEAT * 4;
    __hip_bfloat16* wbuf = (__hip_bfloat16*)(ws + 64 + y_bytes + agg_bytes);

    // adaptive edge-chunk size from remaining workspace (256 B per edge)
    long long avail = (long long)ws_size - (long long)(64 + y_bytes + agg_bytes);
    long long max_edges = avail / (F4 * 2);
    int chunk = E;
    if (max_edges < E) chunk = (int)(max_edges < 16384 ? 16384 : max_edges);

    detect_dtype_kernel<<<1, 1, 0, stream>>>(node_attr, flag);
    hipMemsetAsync(agg, 0, agg_bytes, stream);

    node_y_kernel<<<(N + 1) / 2, 256, 0, stream>>>(node_input, node_attr, Wl10, Wl11, flag, y, N);

    for (int s = 0; s < E; s += chunk) {
        int e_end = s + chunk;
        if (e_end > E) e_end = E;
        int len = e_end - s;
        edge_mlp_kernel<<<(len + 255) / 256, 256, 0, stream>>>(ele, Wfc1, Wfc2, flag, wbuf, s, e_end);
        scatter_kernel<<<(len + TE - 1) / TE, 256, 0, stream>>>(wbuf, y, edge_attr, edge_src,
                                                                edge_dst, flag, agg, s, e_end);
    }

    out_kernel<<<(N + 1) / 2, 256, 0, stream>>>(node_input, node_attr, Wsc0, Wsc1, Wl20, Wl21,
                                                agg, flag, d_out, N);
}

// Round 3
// 996.064 us; speedup vs baseline: 1.4653x; 1.4653x over previous
//
#include <hip/hip_runtime.h>
#include <hip/hip_bf16.h>

#define MUL 32
#define F4 128
#define NB 10
#define NH 100

#define INV_SQRT32 0.17677669529663687f
#define INV_SQRT10 0.31622776601683794f
#define INV_SQRT100 0.1f
#define INV_SQRT3 0.5773502691896258f
#define AGG_SCALE 0.25f   // 1/sqrt(16)
#define INV8 0.125f       // 1/sqrt(64)
#define C_S 0.3826834323650898f
#define C_X 0.9238795325112867f

typedef __attribute__((ext_vector_type(8))) short short8;
typedef __attribute__((ext_vector_type(4))) float float4v;

__device__ __forceinline__ float bf2f(__hip_bfloat16 v) { return __bfloat162float(v); }
__device__ __forceinline__ unsigned short f2b(float x) {
    __hip_bfloat16 b = __float2bfloat16(x);
    return *(unsigned short*)&b;
}
__device__ __forceinline__ float b2f(unsigned short u) {
    __hip_bfloat16 b;
    *(unsigned short*)&b = u;
    return __bfloat162float(b);
}
// flag: 1 = inputs fp32, 0 = inputs bf16
__device__ __forceinline__ float ldin(const void* p, size_t i, int f) {
    return f ? ((const float*)p)[i] : bf2f(((const __hip_bfloat16*)p)[i]);
}

// ---------------------------------------------------------------------------
__global__ void detect_dtype_kernel(const void* __restrict__ node_attr, int* __restrict__ flag) {
    unsigned w = *(const unsigned*)node_attr;
    *flag = (w == 0x3F800000u) ? 1 : 0;
}

// ---------------------------------------------------------------------------
// prep: transpose weights to k-contiguous bf16 for MFMA B-operands.
// w2t[n][k] (128x128, zero-pad k>=100), w20t[v][u] (32x64), w21t[v][u] (32x64)
// ---------------------------------------------------------------------------
__global__ __launch_bounds__(256) void prep_kernel(
    const void* __restrict__ Wfc2,   // 100 x 128
    const void* __restrict__ Wl20,   // 64 x 32
    const void* __restrict__ Wl21,   // 64 x 32
    const int* __restrict__ flagp,
    unsigned short* __restrict__ w2t,
    unsigned short* __restrict__ w20t,
    unsigned short* __restrict__ w21t)
{
    int f = *flagp;
    int t = threadIdx.x;
    for (int i = t; i < 128 * 128; i += 256) {
        int n = i >> 7, k = i & 127;
        w2t[n * 128 + k] = (k < NH) ? f2b(ldin(Wfc2, (size_t)k * 128 + n, f)) : 0;
    }
    for (int i = t; i < 32 * 64; i += 256) {
        int v = i >> 6, u = i & 63;
        w20t[v * 64 + u] = f2b(ldin(Wl20, (size_t)u * 32 + v, f));
        w21t[v * 64 + u] = f2b(ldin(Wl21, (size_t)u * 32 + v, f));
    }
}

// ---------------------------------------------------------------------------
// node_y: y = fctp(x, attr, W_l10, W_l11) -> bf16 [N,128]
// y[n][c]: c<32 -> y0[c]; c>=32 -> y1[u][d] at c = 32 + u*3 + d
// ---------------------------------------------------------------------------
__global__ __launch_bounds__(256) void node_y_kernel(
    const void* __restrict__ node_input,
    const void* __restrict__ node_attr,
    const void* __restrict__ Wl10,
    const void* __restrict__ Wl11,
    const int* __restrict__ flagp,
    unsigned short* __restrict__ y, int N)
{
    __shared__ float sW0[1024];
    __shared__ float sW1[1024];
    __shared__ float sX[2][128];
    int f = *flagp;
    int t = threadIdx.x;
    for (int i = t; i < 1024; i += 256) {
        sW0[i] = ldin(Wl10, i, f);
        sW1[i] = ldin(Wl11, i, f);
    }
    int n0 = blockIdx.x * 2;
    {
        int ln = t >> 7, c = t & 127;
        int n = n0 + ln;
        sX[ln][c] = (n < N) ? ldin(node_input, (size_t)n * F4 + c, f) : 0.f;
    }
    __syncthreads();
    int ln = t >> 7, c = t & 127;
    int n = n0 + ln;
    if (n >= N) return;
    float attr = ldin(node_attr, n, f);
    float acc = 0.f;
    if (c < 32) {
#pragma unroll
        for (int u = 0; u < 32; u++) acc += sX[ln][u] * sW0[u * 32 + c];
    } else {
        int i = c - 32;
        int u0 = i / 3, d = i - u0 * 3;
#pragma unroll
        for (int u = 0; u < 32; u++) acc += sX[ln][32 + u * 3 + d] * sW1[u * 32 + u0];
    }
    y[(size_t)n * F4 + c] = f2b(acc * attr * INV_SQRT32);
}

// ---------------------------------------------------------------------------
// Fused edge kernel: 64 edges/block, 256 threads (4 waves).
// P1: GEMM1+silu (VALU) -> sH bf16 [64][136]; gather y rows -> sY
// P2: GEMM2 via MFMA (h @ W2T) -> sWout bf16 [64][136]
// P3: tensor-product features (scaled) -> sM0 [64][72], sM1 [3][64][72]
// P4: projection MFMA (m0@W20, m1_d@W21)
// P5: atomicAdd into agg [N][128] fp32
// ---------------------------------------------------------------------------
#define SM_W1    0        // float[1000]              4000 B
#define SM_ELE   4000     // float[640]               2560 B
#define SM_H     6560     // ushort[64*136]          17408 B   (aliased by sM1)
#define SM_M1    0        // ushort[3*64*72]         27648 B   (aliases W1/ELE/H)
#define SM_M0    27648    // ushort[64*72]            9216 B
#define SM_WOUT  36864    // ushort[64*136]          17408 B
#define SM_Y     54272    // ushort[64*128]          16384 B
#define SM_EA    70656    // float[256]               1024 B
#define SM_SRC   71680    // int[64]
#define SM_DST   71936    // int[64]
#define SM_TOTAL 72192

__global__ __launch_bounds__(256) void fused_edge_kernel(
    const void* __restrict__ ele,    // E x 10
    const void* __restrict__ Wfc1,   // 10 x 100
    const void* __restrict__ eattr,  // E x 4
    const int* __restrict__ esrc,
    const int* __restrict__ edst,
    const int* __restrict__ flagp,
    const unsigned short* __restrict__ y,     // N x 128 bf16
    const unsigned short* __restrict__ w2t,   // 128 x 128 bf16
    const unsigned short* __restrict__ w20t,  // 32 x 64 bf16
    const unsigned short* __restrict__ w21t,  // 32 x 64 bf16
    float* __restrict__ agg,                  // N x 128 fp32
    int E)
{
    __shared__ __align__(16) char smem[SM_TOTAL];
    float* sW1 = (float*)(smem + SM_W1);
    float* sEle = (float*)(smem + SM_ELE);
    unsigned short* sH = (unsigned short*)(smem + SM_H);
    unsigned short* sM1 = (unsigned short*)(smem + SM_M1);
    unsigned short* sM0 = (unsigned short*)(smem + SM_M0);
    unsigned short* sWout = (unsigned short*)(smem + SM_WOUT);
    unsigned short* sY = (unsigned short*)(smem + SM_Y);
    float* sEa = (float*)(smem + SM_EA);
    int* sSrc = (int*)(smem + SM_SRC);
    int* sDst = (int*)(smem + SM_DST);

    int f = *flagp;
    int t = threadIdx.x;
    int e0 = blockIdx.x * 64;
    int ne = E - e0;
    if (ne > 64) ne = 64;

    // ---- stage 1 ----
    if (t < 64) {
        int ee = e0 + t;
        sSrc[t] = (t < ne) ? esrc[ee] : 0;
        sDst[t] = (t < ne) ? edst[ee] : 0;
    }
    for (int i = t; i < NB * NH; i += 256) sW1[i] = ldin(Wfc1, i, f);
    for (int i = t; i < 64 * NB; i += 256) {
        int e = i / NB;
        sEle[i] = (e < ne) ? ldin(ele, (size_t)e0 * NB + i, f) : 0.f;
    }
    {
        int i = t;  // 256 = 64*4 exactly
        int e = i >> 2;
        sEa[i] = (e < ne) ? ldin(eattr, (size_t)e0 * 4 + i, f) : 0.f;
    }
    __syncthreads();

    // ---- P1: h = silu(ele @ W1 / sqrt(10)) -> sH bf16 (pad k to 128) ----
    {
        int e = t >> 2, p = t & 3;
        float el[NB];
#pragma unroll
        for (int i = 0; i < NB; i++) el[i] = sEle[e * NB + i];
#pragma unroll
        for (int jj = 0; jj < 25; jj++) {
            int j = p * 25 + jj;
            float a = 0.f;
#pragma unroll
            for (int i = 0; i < NB; i++) a += el[i] * sW1[i * NH + j];
            a *= INV_SQRT10;
            sH[e * 136 + j] = f2b(a / (1.f + __expf(-a)));
        }
#pragma unroll
        for (int z = 0; z < 7; z++) sH[e * 136 + 100 + p * 7 + z] = 0;
    }
    // gather y rows (independent of sH)
    for (int i = t; i < 64 * 16; i += 256) {
        int e = i >> 4, q = i & 15;
        ((uint4*)(sY + e * 128))[q] = ((const uint4*)(y + (size_t)sSrc[e] * 128))[q];
    }
    __syncthreads();

    int w = t >> 6, lane = t & 63;
    int lm = lane & 15, quad = lane >> 4;

    // ---- P2: w = h @ W2 * 0.1 via MFMA; tile: wave w -> edges w*16..+15 ----
    {
        float4v acc[8];
#pragma unroll
        for (int nt = 0; nt < 8; nt++) acc[nt] = (float4v){0.f, 0.f, 0.f, 0.f};
        const unsigned short* hrow = sH + (w * 16 + lm) * 136;
#pragma unroll
        for (int kc = 0; kc < 4; kc++) {
            short8 a = *(const short8*)(hrow + kc * 32 + quad * 8);
#pragma unroll
            for (int nt = 0; nt < 8; nt++) {
                short8 b = *(const short8*)(w2t + (nt * 16 + lm) * 128 + kc * 32 + quad * 8);
                acc[nt] = __builtin_amdgcn_mfma_f32_16x16x32_bf16(a, b, acc[nt], 0, 0, 0);
            }
        }
#pragma unroll
        for (int nt = 0; nt < 8; nt++)
#pragma unroll
            for (int r = 0; r < 4; r++)
                sWout[(w * 16 + quad * 4 + r) * 136 + nt * 16 + lm] =
                    f2b(acc[nt][r] * INV_SQRT100);
    }
    __syncthreads();

    // ---- P3: tensor-product features -> sM0 / sM1 (scaled, bf16) ----
    {
        int fc = t;
        int wi, yi, ai, mode;
        if (fc < 32)       { wi = fc;                              yi = fc;               ai = 0;     mode = 0; }
        else if (fc < 64)  { int u = fc - 32;                      wi = 96 + u; yi = 32 + u * 3; ai = 0; mode = 1; }
        else if (fc < 160) { int i = fc - 64; int u = i / 3, d = i - u * 3; wi = 32 + u; yi = u; ai = 1 + d; mode = 0; }
        else               { int i = fc - 160; int u = i / 3, d = i - u * 3; wi = 64 + u; yi = 32 + u * 3 + d; ai = 0; mode = 0; }
        float scale = AGG_SCALE * (mode ? INV_SQRT3 : 1.f);
        unsigned short* wp;
        int woff;
        if (fc < 64) { wp = sM0; woff = fc; }
        else { int q = fc - 64; wp = sM1 + (q % 3) * 4608; woff = q / 3; }
        for (int e = 0; e < ne; e++) {
            float wv = b2f(sWout[e * 136 + wi]);
            float fv;
            if (mode == 0) {
                fv = wv * b2f(sY[e * 128 + yi]) * sEa[e * 4 + ai];
            } else {
                fv = wv * (b2f(sY[e * 128 + yi]) * sEa[e * 4 + 1] +
                           b2f(sY[e * 128 + yi + 1]) * sEa[e * 4 + 2] +
                           b2f(sY[e * 128 + yi + 2]) * sEa[e * 4 + 3]);
            }
            wp[e * 72 + woff] = f2b(fv * scale);
        }
        // zero unwritten rows so MFMA on partial tiles is harmless (values discarded)
        for (int e = ne; e < 64; e++) wp[e * 72 + woff] = 0;
    }
    __syncthreads();

    // ---- P4+P5: project to 128 via MFMA, atomic into agg[N][128] ----
    {
        float4v acc[8];
#pragma unroll
        for (int i = 0; i < 8; i++) acc[i] = (float4v){0.f, 0.f, 0.f, 0.f};
#pragma unroll
        for (int g = 0; g < 4; g++) {
            const unsigned short* mbase =
                (g == 0) ? (sM0 + (w * 16 + lm) * 72) : (sM1 + (g - 1) * 4608 + (w * 16 + lm) * 72);
            const unsigned short* wtg = (g == 0) ? w20t : w21t;
#pragma unroll
            for (int kc = 0; kc < 2; kc++) {
                short8 a = *(const short8*)(mbase + kc * 32 + quad * 8);
#pragma unroll
                for (int nt = 0; nt < 2; nt++) {
                    short8 b = *(const short8*)(wtg + (nt * 16 + lm) * 64 + kc * 32 + quad * 8);
                    acc[g * 2 + nt] = __builtin_amdgcn_mfma_f32_16x16x32_bf16(a, b, acc[g * 2 + nt], 0, 0, 0);
                }
            }
        }
#pragma unroll
        for (int g = 0; g < 4; g++)
#pragma unroll
            for (int nt = 0; nt < 2; nt++)
#pragma unroll
                for (int r = 0; r < 4; r++) {
                    int er = w * 16 + quad * 4 + r;
                    if (er < ne) {
                        int ch = (g == 0) ? (nt * 16 + lm) : (32 + (g - 1) * 32 + nt * 16 + lm);
                        atomicAdd(&agg[(size_t)sDst[er] * F4 + ch], acc[g * 2 + nt][r]);
                    }
                }
    }
}

// ---------------------------------------------------------------------------
// out: out = attr*(c_s * sc(x) + c_x * agg * INV8)
// agg layout: c<32 -> z0[c]; c>=32 -> z1[u][d] at 32 + d*32 + u
// ---------------------------------------------------------------------------
__global__ __launch_bounds__(256) void out_kernel(
    const void* __restrict__ node_input,
    const void* __restrict__ node_attr,
    const void* __restrict__ Wsc0,
    const void* __restrict__ Wsc1,
    const float* __restrict__ agg,   // N x 128
    const int* __restrict__ flagp,
    void* __restrict__ out, int N)
{
    __shared__ float sWs0[1024], sWs1[1024];
    __shared__ float sX[2][128];
    __shared__ float sA[2][128];
    int f = *flagp;
    int t = threadIdx.x;
    for (int i = t; i < 1024; i += 256) {
        sWs0[i] = ldin(Wsc0, i, f);
        sWs1[i] = ldin(Wsc1, i, f);
    }
    int n0 = blockIdx.x * 2;
    {
        int ln = t >> 7, c = t & 127;
        int n = n0 + ln;
        sX[ln][c] = (n < N) ? ldin(node_input, (size_t)n * F4 + c, f) : 0.f;
        sA[ln][c] = (n < N) ? agg[(size_t)n * F4 + c] : 0.f;
    }
    __syncthreads();
    int ln = t >> 7, c = t & 127;
    int n = n0 + ln;
    if (n >= N) return;
    float attr = ldin(node_attr, n, f);
    float s, z;
    if (c < 32) {
        float as = 0.f;
#pragma unroll
        for (int u = 0; u < 32; u++) as += sX[ln][u] * sWs0[u * 32 + c];
        s = as * INV_SQRT32;
        z = sA[ln][c];
    } else {
        int i = c - 32;
        int u0 = i / 3, d = i - u0 * 3;
        float as = 0.f;
#pragma unroll
        for (int u = 0; u < 32; u++) as += sX[ln][32 + u * 3 + d] * sWs1[u * 32 + u0];
        s = as * INV_SQRT32;
        z = sA[ln][32 + d * 32 + u0];
    }
    float val = attr * (C_S * s + C_X * z * INV8);
    size_t oi = (size_t)n * F4 + c;
    if (f) ((float*)out)[oi] = val;
    else   ((__hip_bfloat16*)out)[oi] = __float2bfloat16(val);
}

// ---------------------------------------------------------------------------
extern "C" void kernel_launch(void* const* d_in, const int* in_sizes, int n_in,
                              void* d_out, int out_size, void* d_ws, size_t ws_size,
                              hipStream_t stream) {
    const void* node_input = d_in[0];
    const void* node_attr  = d_in[1];
    const int* edge_src    = (const int*)d_in[2];
    const int* edge_dst    = (const int*)d_in[3];
    const void* edge_attr  = d_in[4];
    const void* ele        = d_in[5];
    const void* Wsc0       = d_in[6];
    const void* Wsc1       = d_in[7];
    const void* Wl10       = d_in[8];
    const void* Wl11       = d_in[9];
    const void* Wl20       = d_in[10];
    const void* Wl21       = d_in[11];
    const void* Wfc1       = d_in[12];
    const void* Wfc2       = d_in[13];

    int N = in_sizes[0] / F4;   // 50000
    int E = in_sizes[2];        // 800000

    char* ws = (char*)d_ws;
    int* flag = (int*)ws;                                        // 64 B
    unsigned short* y = (unsigned short*)(ws + 64);              // N*128 bf16 = 12.8 MB
    size_t y_b = (size_t)N * F4 * 2;
    float* agg = (float*)(ws + 64 + y_b);                        // N*128 fp32 = 25.6 MB
    size_t agg_b = (size_t)N * F4 * 4;
    unsigned short* w2t  = (unsigned short*)(ws + 64 + y_b + agg_b);            // 32 KB
    unsigned short* w20t = (unsigned short*)(ws + 64 + y_b + agg_b + 32768);    // 4 KB
    unsigned short* w21t = (unsigned short*)(ws + 64 + y_b + agg_b + 36864);    // 4 KB

    detect_dtype_kernel<<<1, 1, 0, stream>>>(node_attr, flag);
    prep_kernel<<<1, 256, 0, stream>>>(Wfc2, Wl20, Wl21, flag, w2t, w20t, w21t);
    hipMemsetAsync(agg, 0, agg_b, stream);

    node_y_kernel<<<(N + 1) / 2, 256, 0, stream>>>(node_input, node_attr, Wl10, Wl11, flag, y, N);

    fused_edge_kernel<<<(E + 63) / 64, 256, 0, stream>>>(
        ele, Wfc1, edge_attr, edge_src, edge_dst, flag, y, w2t, w20t, w21t, agg, E);

    out_kernel<<<(N + 1) / 2, 256, 0, stream>>>(node_input, node_attr, Wsc0, Wsc1,
                                                agg, flag, d_out, N);
}

// Round 4
// 668.733 us; speedup vs baseline: 2.1825x; 1.4895x over previous
//
#include <hip/hip_runtime.h>
#include <hip/hip_bf16.h>

#define MUL 32
#define F4 128
#define NB 10
#define NH 100
#define EROW 136   // LDS row stride (ushorts) for sHW / sY: 272 B = 17*16, 16B-aligned rows

#define INV_SQRT32 0.17677669529663687f
#define INV_SQRT10 0.31622776601683794f
#define INV_SQRT100 0.1f
#define INV_SQRT3 0.5773502691896258f
#define AGG_SCALE 0.25f   // 1/sqrt(16)
#define INV8 0.125f       // 1/sqrt(64)
#define C_S 0.3826834323650898f
#define C_X 0.9238795325112867f

typedef __attribute__((ext_vector_type(8))) short short8;
typedef __attribute__((ext_vector_type(4))) float float4v;

__device__ __forceinline__ float bf2f(__hip_bfloat16 v) { return __bfloat162float(v); }
__device__ __forceinline__ unsigned short f2b(float x) {
    __hip_bfloat16 b = __float2bfloat16(x);
    return *(unsigned short*)&b;
}
__device__ __forceinline__ float b2f(unsigned short u) {
    __hip_bfloat16 b;
    *(unsigned short*)&b = u;
    return __bfloat162float(b);
}
// flag: 1 = inputs fp32, 0 = inputs bf16
__device__ __forceinline__ float ldin(const void* p, size_t i, int f) {
    return f ? ((const float*)p)[i] : bf2f(((const __hip_bfloat16*)p)[i]);
}

// ---------------------------------------------------------------------------
__global__ void detect_dtype_kernel(const void* __restrict__ node_attr, int* __restrict__ flag) {
    unsigned w = *(const unsigned*)node_attr;
    *flag = (w == 0x3F800000u) ? 1 : 0;
}

// ---------------------------------------------------------------------------
// prep: k-contiguous bf16 B-operands.
// w2t[n(128)][k(128)] (pad k>=100), w20t[v(32)][k(64)], w21t[v(32)][k(64)],
// w1t[n(112)][k(32)] (pad n>=100, k>=10)
// ---------------------------------------------------------------------------
__global__ __launch_bounds__(256) void prep_kernel(
    const void* __restrict__ Wfc1,   // 10 x 100
    const void* __restrict__ Wfc2,   // 100 x 128
    const void* __restrict__ Wl20,   // 64 x 32
    const void* __restrict__ Wl21,   // 64 x 32
    const int* __restrict__ flagp,
    unsigned short* __restrict__ w1t,
    unsigned short* __restrict__ w2t,
    unsigned short* __restrict__ w20t,
    unsigned short* __restrict__ w21t)
{
    int f = *flagp;
    int t = threadIdx.x;
    for (int i = t; i < 128 * 128; i += 256) {
        int n = i >> 7, k = i & 127;
        w2t[i] = (k < NH) ? f2b(ldin(Wfc2, (size_t)k * 128 + n, f)) : 0;
    }
    for (int i = t; i < 32 * 64; i += 256) {
        int v = i >> 6, u = i & 63;
        w20t[i] = f2b(ldin(Wl20, (size_t)u * 32 + v, f));
        w21t[i] = f2b(ldin(Wl21, (size_t)u * 32 + v, f));
    }
    for (int i = t; i < 112 * 32; i += 256) {
        int n = i >> 5, k = i & 31;
        w1t[i] = (k < NB && n < NH) ? f2b(ldin(Wfc1, (size_t)k * NH + n, f)) : 0;
    }
}

// ---------------------------------------------------------------------------
// node_y: y = fctp(x, attr, W_l10, W_l11) -> bf16 [N,128] PLANAR:
// y[n] = [ y0(32) | y1_d0(u:32) | y1_d1(32) | y1_d2(32) ]
// 16 nodes / block.
// ---------------------------------------------------------------------------
__global__ __launch_bounds__(256) void node_y_kernel(
    const void* __restrict__ node_input,
    const void* __restrict__ node_attr,
    const void* __restrict__ Wl10,
    const void* __restrict__ Wl11,
    const int* __restrict__ flagp,
    unsigned short* __restrict__ y, int N)
{
    __shared__ float sW0[1024];
    __shared__ float sW1[1024];
    __shared__ float sX[16 * 128];
    int f = *flagp;
    int t = threadIdx.x;
    for (int i = t; i < 1024; i += 256) {
        sW0[i] = ldin(Wl10, i, f);
        sW1[i] = ldin(Wl11, i, f);
    }
    int n0 = blockIdx.x * 16;
    for (int i = t; i < 2048; i += 256) {
        int ln = i >> 7, c = i & 127, n = n0 + ln;
        sX[i] = (n < N) ? ldin(node_input, (size_t)n * F4 + c, f) : 0.f;
    }
    __syncthreads();
    for (int i = t; i < 2048; i += 256) {
        int ln = i >> 7, c = i & 127, n = n0 + ln;
        if (n >= N) continue;
        float attr = ldin(node_attr, n, f);
        float acc = 0.f;
        if (c < 32) {
#pragma unroll
            for (int u = 0; u < 32; u++) acc += sX[ln * 128 + u] * sW0[u * 32 + c];
        } else {
            int d = (c - 32) >> 5, u0 = (c - 32) & 31;
#pragma unroll
            for (int u = 0; u < 32; u++) acc += sX[ln * 128 + 32 + u * 3 + d] * sW1[u * 32 + u0];
        }
        y[(size_t)n * F4 + c] = f2b(acc * attr * INV_SQRT32);
    }
}

// ---------------------------------------------------------------------------
// Fused edge kernel: 64 edges/block, 256 threads, 4 blocks/CU.
// P1: h = silu(ele@W1/sqrt10) via MFMA  -> sHW (A-layout rows, k padded 128)
// P2: w = h@W2 *0.1 via MFMA            -> sHW (aliased; frag-read, barrier, overwrite)
// PC: per-lane A-fragment build from b128 LDS reads; 16 MFMA proj; 32 atomics/lane
// ---------------------------------------------------------------------------
#define SM_ELEB  0        // ushort[64*32]   4096
#define SM_HW    4096     // ushort[64*136] 17408
#define SM_Y     21504    // ushort[64*136] 17408
#define SM_EA    38912    // float[64*4]     1024
#define SM_SRC   39936    // int[64]          256
#define SM_DST   40192    // int[64]          256
#define SM_TOTAL 40448    // x4 blocks = 161792 <= 163840

__global__ __launch_bounds__(256, 4) void fused_edge_kernel(
    const void* __restrict__ ele,    // E x 10
    const void* __restrict__ eattr,  // E x 4
    const int* __restrict__ esrc,
    const int* __restrict__ edst,
    const int* __restrict__ flagp,
    const unsigned short* __restrict__ y,     // N x 128 bf16 planar
    const unsigned short* __restrict__ w1t,   // 112 x 32
    const unsigned short* __restrict__ w2t,   // 128 x 128
    const unsigned short* __restrict__ w20t,  // 32 x 64
    const unsigned short* __restrict__ w21t,  // 32 x 64
    float* __restrict__ agg,                  // N x 128 fp32
    int E)
{
    __shared__ __align__(16) char smem[SM_TOTAL];
    unsigned short* sEleB = (unsigned short*)(smem + SM_ELEB);
    unsigned short* sHW = (unsigned short*)(smem + SM_HW);
    unsigned short* sY = (unsigned short*)(smem + SM_Y);
    float* sEa = (float*)(smem + SM_EA);
    int* sSrc = (int*)(smem + SM_SRC);
    int* sDst = (int*)(smem + SM_DST);

    int f = *flagp;
    int t = threadIdx.x;
    int e0 = blockIdx.x * 64;
    int ne = E - e0;
    if (ne > 64) ne = 64;

    // ---- stage ----
    if (t < 64) {
        sSrc[t] = (t < ne) ? esrc[e0 + t] : 0;
        sDst[t] = (t < ne) ? edst[e0 + t] : 0;
    }
    for (int i = t; i < 64 * 32; i += 256) {
        int e = i >> 5, k = i & 31;
        float v = (k < NB && e < ne) ? ldin(ele, (size_t)(e0 + e) * NB + k, f) : 0.f;
        sEleB[i] = f2b(v);
    }
    {
        int e = t >> 2;
        sEa[t] = (e < ne) ? ldin(eattr, (size_t)e0 * 4 + t, f) : 0.f;
    }
    __syncthreads();

    int w = t >> 6, lane = t & 63;
    int lm = lane & 15, quad = lane >> 4;

    // ---- gather y rows (planar) ----
    for (int i = t; i < 64 * 16; i += 256) {
        int e = i >> 4, q = i & 15;
        *(uint4*)(sY + e * EROW + q * 8) = *(const uint4*)(y + (size_t)sSrc[e] * 128 + q * 8);
    }

    // ---- P1: GEMM1 + silu -> sHW ----
    {
        short8 a = *(const short8*)(sEleB + (w * 16 + lm) * 32 + quad * 8);
        float4v c1[7];
#pragma unroll
        for (int nt = 0; nt < 7; nt++) {
            c1[nt] = (float4v){0.f, 0.f, 0.f, 0.f};
            short8 b = *(const short8*)(w1t + (nt * 16 + lm) * 32 + quad * 8);
            c1[nt] = __builtin_amdgcn_mfma_f32_16x16x32_bf16(a, b, c1[nt], 0, 0, 0);
        }
#pragma unroll
        for (int nt = 0; nt < 7; nt++) {
            int ch = nt * 16 + lm;
#pragma unroll
            for (int r = 0; r < 4; r++) {
                int row = w * 16 + quad * 4 + r;
                float hv = 0.f;
                if (ch < NH) {
                    float aa = c1[nt][r] * INV_SQRT10;
                    hv = aa / (1.f + __expf(-aa));
                }
                sHW[row * EROW + ch] = f2b(hv);
            }
        }
        // zero k in [112,128)
        int e = t >> 2, seg = t & 3;
        *(uint2*)(sHW + e * EROW + 112 + seg * 4) = (uint2){0u, 0u};
    }
    __syncthreads();

    // ---- P2: GEMM2 (read h frags, barrier, overwrite with wout) ----
    short8 a2[4];
#pragma unroll
    for (int kc = 0; kc < 4; kc++)
        a2[kc] = *(const short8*)(sHW + (w * 16 + lm) * EROW + kc * 32 + quad * 8);
    __syncthreads();
    {
        float4v c2[8];
#pragma unroll
        for (int nt = 0; nt < 8; nt++) c2[nt] = (float4v){0.f, 0.f, 0.f, 0.f};
#pragma unroll
        for (int kc = 0; kc < 4; kc++) {
#pragma unroll
            for (int nt = 0; nt < 8; nt++) {
                short8 b = *(const short8*)(w2t + (nt * 16 + lm) * 128 + kc * 32 + quad * 8);
                c2[nt] = __builtin_amdgcn_mfma_f32_16x16x32_bf16(a2[kc], b, c2[nt], 0, 0, 0);
            }
        }
#pragma unroll
        for (int nt = 0; nt < 8; nt++)
#pragma unroll
            for (int r = 0; r < 4; r++)
                sHW[(w * 16 + quad * 4 + r) * EROW + nt * 16 + lm] = f2b(c2[nt][r] * INV_SQRT100);
    }
    __syncthreads();

    // ---- PC: build A-frags in regs, project via MFMA, atomics ----
    {
        int em = w * 16 + lm;
        const unsigned short* wr = sHW + em * EROW;
        const unsigned short* yr = sY + em * EROW;
        short8 wA = *(const short8*)(wr + quad * 8);
        short8 wB = *(const short8*)(wr + 32 + quad * 8);
        short8 wC = *(const short8*)(wr + 64 + quad * 8);
        short8 wD = *(const short8*)(wr + 96 + quad * 8);
        short8 x0 = *(const short8*)(yr + quad * 8);
        short8 xd0 = *(const short8*)(yr + 32 + quad * 8);
        short8 xd1 = *(const short8*)(yr + 64 + quad * 8);
        short8 xd2 = *(const short8*)(yr + 96 + quad * 8);
        float ea0 = sEa[em * 4 + 0];
        float e1x = sEa[em * 4 + 1];
        float e1y = sEa[em * 4 + 2];
        float e1z = sEa[em * 4 + 3];
        float ea0S = ea0 * AGG_SCALE;
        float s3 = AGG_SCALE * INV_SQRT3;

        short8 f00, f01, f10, f11, f20, f21, f30, f31;
#pragma unroll
        for (int j = 0; j < 8; j++) {
            float x0f = b2f((unsigned short)x0[j]);
            float d0f = b2f((unsigned short)xd0[j]);
            float d1f = b2f((unsigned short)xd1[j]);
            float d2f = b2f((unsigned short)xd2[j]);
            f00[j] = (short)f2b(b2f((unsigned short)wA[j]) * x0f * ea0S);
            float tt = d0f * e1x + d1f * e1y + d2f * e1z;
            f01[j] = (short)f2b(b2f((unsigned short)wD[j]) * tt * s3);
            float p = b2f((unsigned short)wB[j]) * x0f * AGG_SCALE;
            f10[j] = (short)f2b(p * e1x);
            f20[j] = (short)f2b(p * e1y);
            f30[j] = (short)f2b(p * e1z);
            float q = b2f((unsigned short)wC[j]) * ea0S;
            f11[j] = (short)f2b(q * d0f);
            f21[j] = (short)f2b(q * d1f);
            f31[j] = (short)f2b(q * d2f);
        }

        float4v acc[8];
#pragma unroll
        for (int i = 0; i < 8; i++) acc[i] = (float4v){0.f, 0.f, 0.f, 0.f};
#pragma unroll
        for (int g = 0; g < 4; g++) {
            const unsigned short* wt = g ? w21t : w20t;
            short8 ak0 = (g == 0) ? f00 : (g == 1) ? f10 : (g == 2) ? f20 : f30;
            short8 ak1 = (g == 0) ? f01 : (g == 1) ? f11 : (g == 2) ? f21 : f31;
#pragma unroll
            for (int nt = 0; nt < 2; nt++) {
                short8 b0 = *(const short8*)(wt + (nt * 16 + lm) * 64 + quad * 8);
                short8 b1 = *(const short8*)(wt + (nt * 16 + lm) * 64 + 32 + quad * 8);
                acc[g * 2 + nt] = __builtin_amdgcn_mfma_f32_16x16x32_bf16(ak0, b0, acc[g * 2 + nt], 0, 0, 0);
                acc[g * 2 + nt] = __builtin_amdgcn_mfma_f32_16x16x32_bf16(ak1, b1, acc[g * 2 + nt], 0, 0, 0);
            }
        }
#pragma unroll
        for (int g = 0; g < 4; g++)
#pragma unroll
            for (int nt = 0; nt < 2; nt++)
#pragma unroll
                for (int r = 0; r < 4; r++) {
                    int er = w * 16 + quad * 4 + r;
                    if (er < ne) {
                        int ch = (g == 0) ? (nt * 16 + lm) : (32 + (g - 1) * 32 + nt * 16 + lm);
                        atomicAdd(&agg[(size_t)sDst[er] * F4 + ch], acc[g * 2 + nt][r]);
                    }
                }
    }
}

// ---------------------------------------------------------------------------
// out: out = attr*(c_s * sc(x) + c_x * agg * INV8); 16 nodes/block
// agg layout: c<32 -> z0[c]; z1[u][d] at 32 + d*32 + u
// ---------------------------------------------------------------------------
__global__ __launch_bounds__(256) void out_kernel(
    const void* __restrict__ node_input,
    const void* __restrict__ node_attr,
    const void* __restrict__ Wsc0,
    const void* __restrict__ Wsc1,
    const float* __restrict__ agg,   // N x 128
    const int* __restrict__ flagp,
    void* __restrict__ out, int N)
{
    __shared__ float sWs0[1024], sWs1[1024];
    __shared__ float sX[16 * 128];
    __shared__ float sA[16 * 128];
    int f = *flagp;
    int t = threadIdx.x;
    for (int i = t; i < 1024; i += 256) {
        sWs0[i] = ldin(Wsc0, i, f);
        sWs1[i] = ldin(Wsc1, i, f);
    }
    int n0 = blockIdx.x * 16;
    for (int i = t; i < 2048; i += 256) {
        int ln = i >> 7, c = i & 127, n = n0 + ln;
        sX[i] = (n < N) ? ldin(node_input, (size_t)n * F4 + c, f) : 0.f;
        sA[i] = (n < N) ? agg[(size_t)n * F4 + c] : 0.f;
    }
    __syncthreads();
    for (int i = t; i < 2048; i += 256) {
        int ln = i >> 7, c = i & 127, n = n0 + ln;
        if (n >= N) continue;
        float attr = ldin(node_attr, n, f);
        float s, z;
        if (c < 32) {
            float as = 0.f;
#pragma unroll
            for (int u = 0; u < 32; u++) as += sX[ln * 128 + u] * sWs0[u * 32 + c];
            s = as * INV_SQRT32;
            z = sA[ln * 128 + c];
        } else {
            int i2 = c - 32;
            int u0 = i2 / 3, d = i2 - u0 * 3;
            float as = 0.f;
#pragma unroll
            for (int u = 0; u < 32; u++) as += sX[ln * 128 + 32 + u * 3 + d] * sWs1[u * 32 + u0];
            s = as * INV_SQRT32;
            z = sA[ln * 128 + 32 + d * 32 + u0];
        }
        float val = attr * (C_S * s + C_X * z * INV8);
        size_t oi = (size_t)n * F4 + c;
        if (f) ((float*)out)[oi] = val;
        else   ((__hip_bfloat16*)out)[oi] = __float2bfloat16(val);
    }
}

// ---------------------------------------------------------------------------
extern "C" void kernel_launch(void* const* d_in, const int* in_sizes, int n_in,
                              void* d_out, int out_size, void* d_ws, size_t ws_size,
                              hipStream_t stream) {
    const void* node_input = d_in[0];
    const void* node_attr  = d_in[1];
    const int* edge_src    = (const int*)d_in[2];
    const int* edge_dst    = (const int*)d_in[3];
    const void* edge_attr  = d_in[4];
    const void* ele        = d_in[5];
    const void* Wsc0       = d_in[6];
    const void* Wsc1       = d_in[7];
    const void* Wl10       = d_in[8];
    const void* Wl11       = d_in[9];
    const void* Wl20       = d_in[10];
    const void* Wl21       = d_in[11];
    const void* Wfc1       = d_in[12];
    const void* Wfc2       = d_in[13];

    int N = in_sizes[0] / F4;   // 50000
    int E = in_sizes[2];        // 800000

    char* ws = (char*)d_ws;
    int* flag = (int*)ws;                                        // 64 B
    unsigned short* y = (unsigned short*)(ws + 64);              // N*128 bf16
    size_t y_b = (size_t)N * F4 * 2;
    float* agg = (float*)(ws + 64 + y_b);                        // N*128 fp32
    size_t agg_b = (size_t)N * F4 * 4;
    size_t off = 64 + y_b + agg_b;
    unsigned short* w2t  = (unsigned short*)(ws + off);          // 32 KB
    unsigned short* w20t = (unsigned short*)(ws + off + 32768);  // 4 KB
    unsigned short* w21t = (unsigned short*)(ws + off + 36864);  // 4 KB
    unsigned short* w1t  = (unsigned short*)(ws + off + 40960);  // 7 KB

    detect_dtype_kernel<<<1, 1, 0, stream>>>(node_attr, flag);
    prep_kernel<<<1, 256, 0, stream>>>(Wfc1, Wfc2, Wl20, Wl21, flag, w1t, w2t, w20t, w21t);
    hipMemsetAsync(agg, 0, agg_b, stream);

    node_y_kernel<<<(N + 15) / 16, 256, 0, stream>>>(node_input, node_attr, Wl10, Wl11, flag, y, N);

    fused_edge_kernel<<<(E + 63) / 64, 256, 0, stream>>>(
        ele, edge_attr, edge_src, edge_dst, flag, y, w1t, w2t, w20t, w21t, agg, E);

    out_kernel<<<(N + 15) / 16, 256, 0, stream>>>(node_input, node_attr, Wsc0, Wsc1,
                                                  agg, flag, d_out, N);
}